// Round 3
// baseline (10603.329 us; speedup 1.0000x reference)
//
#include <hip/hip_runtime.h>
#include <hip/hip_bf16.h>
#include <stdint.h>
#include <string.h>

// Problem constants
#define HD   512          // hidden
#define BD   64           // batch
#define TD   512          // timesteps (S*W = 16*32)
#define ED   300          // input embed
#define EPD  320          // padded embed (mult of 32)
#define NKB  26           // fused K blocks of 32: 16 (h) + 10 (x)
#define NKH  16           // h K-blocks
#define NKX  10           // x K-blocks
#define NWG  64           // total WGs
#define NWGD 32           // WGs per direction
#define JS   16           // h-columns per WG
#define NT   4            // 16-wide N-tiles per WG (JS*4 gates / 16) == waves
#define SLICE_BYTES (BD * JS * 2)   // 2048 B packed h block per slice

typedef __attribute__((ext_vector_type(8))) short bf16x8;
typedef __attribute__((ext_vector_type(4))) float f32x4;

__device__ __forceinline__ float sigm_f(float x) {
    return __builtin_amdgcn_rcpf(1.0f + __expf(-x));
}
__device__ __forceinline__ float tanh_f(float x) {
    return fmaf(2.0f, __builtin_amdgcn_rcpf(1.0f + __expf(-2.0f * x)), -1.0f);
}

// agent-scope (cross-XCD safe) primitives
union HU { unsigned long long u[2]; bf16x8 v; };
__device__ __forceinline__ bf16x8 ld_h16(const void* p) {
    HU r;
    const unsigned long long* q = (const unsigned long long*)p;
    r.u[0] = __hip_atomic_load(q,     __ATOMIC_RELAXED, __HIP_MEMORY_SCOPE_AGENT);
    r.u[1] = __hip_atomic_load(q + 1, __ATOMIC_RELAXED, __HIP_MEMORY_SCOPE_AGENT);
    return r.v;
}
__device__ __forceinline__ void st64(unsigned long long* p, unsigned long long v) {
    __hip_atomic_store(p, v, __ATOMIC_RELAXED, __HIP_MEMORY_SCOPE_AGENT);
}

// ---- kernel 0: cast input x [B][T][300] f32 -> [B][T][320] bf16 (zero pad) ----
__global__ __launch_bounds__(256) void cast_x_kernel(const float* __restrict__ x,
                                                     __hip_bfloat16* __restrict__ xb) {
    int i = blockIdx.x * 256 + threadIdx.x;
    int e = i % EPD;
    int bt = i / EPD;
    float v = (e < ED) ? x[bt * ED + e] : 0.0f;
    xb[i] = __float2bfloat16(v);
}

// ---- kernel 1: persistent bidirectional LSTM ----
// WG: d = wg>>5, slice = wg&31, j0 = slice*16. Wave nw handles N-tile nw
// (16 gate-cols: q = c&3, jj = nw*4 + (c>>2)) for ALL 4 M-tiles (64 batches).
// h exchange: packed [parity][dir][slice][batch][16 cols] bf16 blocks (2 KB),
// written as ONE coalesced 8B/thread sc1 store via LDS staging.
__global__ __launch_bounds__(256, 1) void lstm_persistent(
    const __hip_bfloat16* __restrict__ xb,
    const float* __restrict__ wih_f, const float* __restrict__ whh_f, const float* __restrict__ bias_f,
    const float* __restrict__ wih_b, const float* __restrict__ whh_b, const float* __restrict__ bias_b,
    char* h_buf,             // packed, 2*2*NWGD*SLICE_BYTES
    float* wmaxp,            // [2 dir][16 seg][B][H] f32
    unsigned* bar)           // 8 counter lines x 128B
{
    __shared__ __hip_bfloat16 wlds[NT][NKB][64][8];          // 106,496 B
    __shared__ __align__(8) __hip_bfloat16 hstage[BD][JS];   // 2,048 B

    const int wg = blockIdx.x;
    const int d = wg >> 5;
    const int slice = wg & 31;
    const int j0 = slice * JS;
    const int tid = threadIdx.x;
    const int lane = tid & 63;
    const int nw = tid >> 6;      // wave id == N-tile id
    const int c = lane & 15;      // column within 16-wide tile
    const int q = c & 3;          // gate: 0=i 1=f 2=g~ 3=o
    const int g16 = lane >> 4;    // 0..3
    const int cl = lane & 15;

    const float* WHH  = d ? whh_b  : whh_f;
    const float* WIH  = d ? wih_b  : wih_f;
    const float* BIAS = d ? bias_b : bias_f;

    // --- weights (f32 -> bf16) into LDS, B-fragment-ordered ---
    for (int slot = tid; slot < NT * NKB * 64; slot += 256) {
        int l = slot & 63;
        int rest = slot >> 6;
        int kb = rest % NKB;
        int nt = rest / NKB;
        int cc = l & 15;
        int qq = cc & 3;
        int jj = nt * 4 + (cc >> 2);
        int gr = qq * HD + j0 + jj;
        int kbase = kb * 32 + ((l >> 4) << 3);
        __hip_bfloat16 tmp[8];
        #pragma unroll
        for (int e = 0; e < 8; ++e) {
            int k = kbase + e;
            float v;
            if (k < HD) v = WHH[gr * HD + k];
            else {
                int ke = k - HD;
                v = (ke < ED) ? WIH[gr * ED + ke] : 0.0f;
            }
            tmp[e] = __float2bfloat16(v);
        }
        *reinterpret_cast<bf16x8*>(&wlds[nt][kb][l][0]) = *reinterpret_cast<bf16x8*>(tmp);
    }

    const float bias_n = BIAS[q * HD + j0 + nw * 4 + (c >> 2)];

    // --- h0 = 0: zero our packed slice block (parity 0) ---
    {
        unsigned long long* hp0 =
            (unsigned long long*)(h_buf + ((size_t)(0 * 2 + d) * NWGD + slice) * SLICE_BYTES);
        st64(hp0 + tid, 0ull);
    }

    unsigned* my_line   = bar + (d * 4 + (slice & 3)) * 32;  // 128B apart
    unsigned* dir_lines = bar + d * 4 * 32;

    #define ARRIVE() do { \
        asm volatile("s_waitcnt vmcnt(0)" ::: "memory"); \
        __syncthreads(); \
        if (tid == 0) __hip_atomic_fetch_add(my_line, 1u, __ATOMIC_RELAXED, __HIP_MEMORY_SCOPE_AGENT); \
    } while (0)
    #define WAITFOR(target) do { \
        if (tid == 0) { \
            for (;;) { \
                unsigned s_ = 0; \
                _Pragma("unroll") \
                for (int i_ = 0; i_ < 4; ++i_) \
                    s_ += __hip_atomic_load(dir_lines + i_ * 32, __ATOMIC_RELAXED, __HIP_MEMORY_SCOPE_AGENT); \
                if (s_ >= (target)) break; \
                __builtin_amdgcn_s_sleep(1); \
            } \
        } \
        __syncthreads(); \
    } while (0)

    ARRIVE();   // barrier 0: weights(LDS) + h0 visible; per-dir sum -> 32

    // recurrent state on owner lanes (q==0): batch = m*16 + g16*4 + r
    float c_st[4][4];
    float wm[4][4];
    #pragma unroll
    for (int m = 0; m < 4; ++m)
        #pragma unroll
        for (int r = 0; r < 4; ++r) { c_st[m][r] = 0.f; wm[m][r] = -3.0e38f; }

    // prologue: x-part accumulators for t=0
    f32x4 ax[4];
    {
        int te = d ? (TD - 1) : 0;
        #pragma unroll
        for (int m = 0; m < 4; ++m) {
            ax[m][0] = ax[m][1] = ax[m][2] = ax[m][3] = 0.f;
            const __hip_bfloat16* xr = xb + ((size_t)(m * 16 + cl) * TD + te) * EPD + (g16 << 3);
            #pragma unroll
            for (int kb = 0; kb < NKX; ++kb) {
                bf16x8 a = *reinterpret_cast<const bf16x8*>(xr + kb * 32);
                bf16x8 b = *reinterpret_cast<const bf16x8*>(&wlds[nw][NKH + kb][lane][0]);
                ax[m] = __builtin_amdgcn_mfma_f32_16x16x32_bf16(a, b, ax[m], 0, 0, 0);
            }
        }
    }

    for (int t = 0; t < TD; ++t) {
        WAITFOR((unsigned)(t + 1) * NWGD);

        const char* hin = h_buf + (size_t)((t & 1) * 2 + d) * (NWGD * SLICE_BYTES);

        f32x4 acc[4];
        #pragma unroll
        for (int m = 0; m < 4; ++m) acc[m] = ax[m];

        // h-part: packed A-frag address: slice_g = kb*2 + (g16>>1),
        // byte = slice_g*2048 + batch*32 + (g16&1)*16
        #pragma unroll
        for (int kb = 0; kb < NKH; ++kb) {
            const char* hk = hin + (size_t)(kb * 2 + (g16 >> 1)) * SLICE_BYTES + ((g16 & 1) << 4);
            bf16x8 b = *reinterpret_cast<const bf16x8*>(&wlds[nw][kb][lane][0]);
            #pragma unroll
            for (int m = 0; m < 4; ++m) {
                bf16x8 a = ld_h16(hk + (m * 16 + cl) * 32);
                acc[m] = __builtin_amdgcn_mfma_f32_16x16x32_bf16(a, b, acc[m], 0, 0, 0);
            }
        }

        // activations: each lane activates its own gate column
        float aown[4][4];
        #pragma unroll
        for (int m = 0; m < 4; ++m)
            #pragma unroll
            for (int r = 0; r < 4; ++r) {
                float v = acc[m][r] + bias_n;
                aown[m][r] = (q == 2) ? tanh_f(v) : sigm_f(v);
            }
        // gather f,g,o to owner lanes (q==0)
        #pragma unroll
        for (int m = 0; m < 4; ++m) {
            #pragma unroll
            for (int r = 0; r < 4; ++r) {
                float fv = __shfl_xor(aown[m][r], 1, 64);
                float gv = __shfl_xor(aown[m][r], 2, 64);
                float ov = __shfl_xor(aown[m][r], 3, 64);
                if (q == 0) {
                    float iv = aown[m][r];
                    float cn = fmaf(fv, c_st[m][r], iv * gv);
                    c_st[m][r] = cn;
                    float hn = ov * tanh_f(cn);
                    wm[m][r] = fmaxf(wm[m][r], hn);
                    int batch = m * 16 + (g16 << 2) + r;
                    hstage[batch][nw * 4 + (c >> 2)] = __float2bfloat16(hn);
                }
            }
        }

        __syncthreads();  // hstage complete (cross-wave)

        // ONE coalesced 8B sc1 store per thread: whole 2KB slice block
        {
            unsigned long long v = ((const unsigned long long*)&hstage[0][0])[tid];
            unsigned long long* hout = (unsigned long long*)(
                h_buf + (size_t)(((t + 1) & 1) * 2 + d) * (NWGD * SLICE_BYTES)
                      + (size_t)slice * SLICE_BYTES);
            st64(hout + tid, v);
        }

        ARRIVE();   // per-dir sum -> 32*(t+2)

        // off-critical-path bookkeeping
        if ((t & 31) == 31 && q == 0) {
            int seg = t >> 5;
            if (d) seg = 15 - seg;
            int col = j0 + nw * 4 + (c >> 2);
            #pragma unroll
            for (int m = 0; m < 4; ++m)
                #pragma unroll
                for (int r = 0; r < 4; ++r) {
                    int batch = m * 16 + (g16 << 2) + r;
                    wmaxp[((d * 16 + seg) * BD + batch) * HD + col] = wm[m][r];
                    wm[m][r] = -3.0e38f;
                }
        }

        // pipelined x-part for t+1 (independent of h_{t+1})
        if (t + 1 < TD) {
            int te = d ? (TD - 2 - t) : (t + 1);
            #pragma unroll
            for (int m = 0; m < 4; ++m) {
                f32x4 nx = {0.f, 0.f, 0.f, 0.f};
                const __hip_bfloat16* xr = xb + ((size_t)(m * 16 + cl) * TD + te) * EPD + (g16 << 3);
                #pragma unroll
                for (int kb = 0; kb < NKX; ++kb) {
                    bf16x8 a = *reinterpret_cast<const bf16x8*>(xr + kb * 32);
                    bf16x8 b = *reinterpret_cast<const bf16x8*>(&wlds[nw][NKH + kb][lane][0]);
                    nx = __builtin_amdgcn_mfma_f32_16x16x32_bf16(a, b, nx, 0, 0, 0);
                }
                ax[m] = nx;
            }
        }
    }
    #undef ARRIVE
    #undef WAITFOR
}

// ---- kernel 2: window-max sum, segment max, decode ----
__global__ __launch_bounds__(256) void pool_decode(const float* __restrict__ wmaxp,
                                                   const float* __restrict__ wdec,
                                                   const float* __restrict__ bdec,
                                                   float* __restrict__ out) {
    __shared__ float red[4 * 256];
    int b = blockIdx.x;
    int tid = threadIdx.x;
    float p[4] = {0.f, 0.f, 0.f, 0.f};
    for (int j = tid; j < HD; j += 256) {
        float m = -3.0e38f;
        #pragma unroll
        for (int s = 0; s < 16; ++s) {
            float v = wmaxp[((0 * 16 + s) * BD + b) * HD + j] +
                      wmaxp[((1 * 16 + s) * BD + b) * HD + j];
            m = fmaxf(m, v);
        }
        m = fmaxf(m, 0.0f);
        #pragma unroll
        for (int q2 = 0; q2 < 4; ++q2) p[q2] = fmaf(m, wdec[q2 * HD + j], p[q2]);
    }
    #pragma unroll
    for (int q2 = 0; q2 < 4; ++q2) red[q2 * 256 + tid] = p[q2];
    __syncthreads();
    for (int off = 128; off > 0; off >>= 1) {
        if (tid < off) {
            #pragma unroll
            for (int q2 = 0; q2 < 4; ++q2) red[q2 * 256 + tid] += red[q2 * 256 + tid + off];
        }
        __syncthreads();
    }
    if (tid < 4) {
        float logit = red[tid * 256] + bdec[tid];
        out[b * 4 + tid] = sigm_f(logit);
    }
}

extern "C" void kernel_launch(void* const* d_in, const int* in_sizes, int n_in,
                              void* d_out, int out_size, void* d_ws, size_t ws_size,
                              hipStream_t stream) {
    (void)in_sizes; (void)n_in; (void)out_size; (void)ws_size;
    const float* x     = (const float*)d_in[0];
    const float* wih_f = (const float*)d_in[1];
    const float* whh_f = (const float*)d_in[2];
    const float* b_f   = (const float*)d_in[3];
    const float* wih_b = (const float*)d_in[4];
    const float* whh_b = (const float*)d_in[5];
    const float* b_b   = (const float*)d_in[6];
    const float* wdec  = (const float*)d_in[7];
    const float* bdec  = (const float*)d_in[8];

    char* ws = (char*)d_ws;
    unsigned* bar = (unsigned*)ws;                           // 1024 B: 8 lines x 128B
    __hip_bfloat16* xb = (__hip_bfloat16*)(ws + 2048);       // BD*TD*EPD*2 = 20,971,520 B
    size_t off = 2048 + (size_t)BD * TD * EPD * 2;
    char* hbuf = ws + off;                                   // 2*2*32*2048 = 262,144 B
    off += (size_t)2 * 2 * NWGD * SLICE_BYTES;
    float* wmaxp = (float*)(ws + off);                       // 2*16*BD*HD*4 = 4,194,304 B

    hipMemsetAsync(bar, 0, 2048, stream);
    cast_x_kernel<<<dim3((BD * TD * EPD) / 256), dim3(256), 0, stream>>>(x, xb);

    const __hip_bfloat16* xb_c = xb;
    char* hbuf_p = hbuf;
    float* wmax_p = wmaxp;
    unsigned* bar_p = bar;
    void* args[] = {(void*)&xb_c, (void*)&wih_f, (void*)&whh_f, (void*)&b_f,
                    (void*)&wih_b, (void*)&whh_b, (void*)&b_b,
                    (void*)&hbuf_p, (void*)&wmax_p, (void*)&bar_p};
    hipLaunchCooperativeKernel((void*)lstm_persistent, dim3(NWG), dim3(256), args, 0, stream);

    pool_decode<<<dim3(BD), dim3(256), 0, stream>>>(wmaxp, wdec, bdec, (float*)d_out);
}

// Round 4
// 2899.167 us; speedup vs baseline: 3.6574x; 3.6574x over previous
//
#include <hip/hip_runtime.h>
#include <hip/hip_bf16.h>
#include <stdint.h>
#include <string.h>

// Problem constants
#define HD   512          // hidden
#define BD   64           // batch
#define TD   512          // timesteps (S*W = 16*32)
#define ED   300          // input embed
#define EPD  320          // padded embed (mult of 32)
#define NKB  26           // fused K blocks of 32: 16 (h) + 10 (x)
#define NKH  16           // h K-blocks
#define NKX  10           // x K-blocks
#define NWG  128          // total WGs
#define NWGD 64           // WGs per direction
#define JS   8            // h-columns per WG
#define NT   2            // 16-wide N-tiles per WG
#define SLICE_BYTES (BD * JS * 2)   // 1024 B packed h block per slice

typedef __attribute__((ext_vector_type(8))) short bf16x8;
typedef __attribute__((ext_vector_type(4))) float f32x4;

__device__ __forceinline__ float sigm_f(float x) {
    return __builtin_amdgcn_rcpf(1.0f + __expf(-x));
}
__device__ __forceinline__ float tanh_f(float x) {
    return fmaf(2.0f, __builtin_amdgcn_rcpf(1.0f + __expf(-2.0f * x)), -1.0f);
}

// agent-scope (cross-XCD safe) primitives
union HU { unsigned long long u[2]; bf16x8 v; };
__device__ __forceinline__ bf16x8 ld_h16(const void* p) {
    HU r;
    const unsigned long long* q = (const unsigned long long*)p;
    r.u[0] = __hip_atomic_load(q,     __ATOMIC_RELAXED, __HIP_MEMORY_SCOPE_AGENT);
    r.u[1] = __hip_atomic_load(q + 1, __ATOMIC_RELAXED, __HIP_MEMORY_SCOPE_AGENT);
    return r.v;
}
__device__ __forceinline__ void st64(unsigned long long* p, unsigned long long v) {
    __hip_atomic_store(p, v, __ATOMIC_RELAXED, __HIP_MEMORY_SCOPE_AGENT);
}

// ---- kernel 0: cast input x [B][T][300] f32 -> [B][T][320] bf16 (zero pad) ----
__global__ __launch_bounds__(256) void cast_x_kernel(const float* __restrict__ x,
                                                     __hip_bfloat16* __restrict__ xb) {
    int i = blockIdx.x * 256 + threadIdx.x;
    int e = i % EPD;
    int bt = i / EPD;
    float v = (e < ED) ? x[bt * ED + e] : 0.0f;
    xb[i] = __float2bfloat16(v);
}

// ---- kernel 1: persistent bidirectional LSTM ----
// 128 WGs: d = wg>>6, slice = wg&63, j0 = slice*8 (8 h-cols, 32 gate-cols).
// Wave wv owns M-tile wv (batches wv*16..+15) x BOTH N-tiles (A-reuse):
// 16 MALL h-loads per wave per step (one register burst), 32 MFMAs.
// h exchange: packed [parity][dir][slice][batch][8 cols] bf16 (1 KB/slice),
// exported via LDS stage as ONE coalesced 8B/thread sc1 store.
__global__ __launch_bounds__(256, 1) void lstm_persistent(
    const __hip_bfloat16* __restrict__ xb,
    const float* __restrict__ wih_f, const float* __restrict__ whh_f, const float* __restrict__ bias_f,
    const float* __restrict__ wih_b, const float* __restrict__ whh_b, const float* __restrict__ bias_b,
    char* h_buf,             // packed, 2*2*NWGD*SLICE_BYTES
    float* wmaxp,            // [2 dir][16 seg][B][H] f32
    unsigned* bar)           // 16 counter lines x 128B
{
    __shared__ __hip_bfloat16 wlds[NT][NKB][64][8];          // 53,248 B
    __shared__ __align__(8) __hip_bfloat16 hstage[BD][JS];   // 1,024 B

    const int wg = blockIdx.x;
    const int d = wg >> 6;
    const int slice = wg & 63;
    const int j0 = slice * JS;
    const int tid = threadIdx.x;
    const int lane = tid & 63;
    const int wv = tid >> 6;      // wave id == M-tile id
    const int c = lane & 15;      // column within 16-wide N-tile
    const int q = c & 3;          // gate: 0=i 1=f 2=g~ 3=o
    const int g16 = lane >> 4;    // 0..3
    const int cl = lane & 15;

    const float* WHH  = d ? whh_b  : whh_f;
    const float* WIH  = d ? wih_b  : wih_f;
    const float* BIAS = d ? bias_b : bias_f;

    // --- weights (f32 -> bf16) into LDS, B-fragment-ordered ---
    for (int slot = tid; slot < NT * NKB * 64; slot += 256) {
        int l = slot & 63;
        int rest = slot >> 6;
        int kb = rest % NKB;
        int nt = rest / NKB;
        int cc = l & 15;
        int qq = cc & 3;
        int jj = nt * 4 + (cc >> 2);
        int gr = qq * HD + j0 + jj;
        int kbase = kb * 32 + ((l >> 4) << 3);
        __hip_bfloat16 tmp[8];
        #pragma unroll
        for (int e = 0; e < 8; ++e) {
            int k = kbase + e;
            float v;
            if (k < HD) v = WHH[gr * HD + k];
            else {
                int ke = k - HD;
                v = (ke < ED) ? WIH[gr * ED + ke] : 0.0f;
            }
            tmp[e] = __float2bfloat16(v);
        }
        *reinterpret_cast<bf16x8*>(&wlds[nt][kb][l][0]) = *reinterpret_cast<bf16x8*>(tmp);
    }

    float bias_n[NT];
    #pragma unroll
    for (int nt = 0; nt < NT; ++nt)
        bias_n[nt] = BIAS[q * HD + j0 + nt * 4 + (c >> 2)];

    // --- h0 = 0: zero our packed slice block (parity 0) ---
    {
        unsigned long long* hp0 =
            (unsigned long long*)(h_buf + ((size_t)(0 * 2 + d) * NWGD + slice) * SLICE_BYTES);
        if (tid < SLICE_BYTES / 8) st64(hp0 + tid, 0ull);
    }

    unsigned* my_line   = bar + (d * 8 + (slice & 7)) * 32;  // 128B apart
    unsigned* dir_lines = bar + d * 8 * 32;

    #define ARRIVE() do { \
        asm volatile("s_waitcnt vmcnt(0)" ::: "memory"); \
        __syncthreads(); \
        if (tid == 0) __hip_atomic_fetch_add(my_line, 1u, __ATOMIC_RELAXED, __HIP_MEMORY_SCOPE_AGENT); \
    } while (0)
    #define WAITFOR(target) do { \
        if (tid == 0) { \
            for (;;) { \
                unsigned s_ = 0; \
                _Pragma("unroll") \
                for (int i_ = 0; i_ < 8; ++i_) \
                    s_ += __hip_atomic_load(dir_lines + i_ * 32, __ATOMIC_RELAXED, __HIP_MEMORY_SCOPE_AGENT); \
                if (s_ >= (target)) break; \
                __builtin_amdgcn_s_sleep(1); \
            } \
        } \
        __syncthreads(); \
    } while (0)

    ARRIVE();   // barrier 0: weights(LDS) + h0 visible; per-dir sum -> 64

    // owner-lane (q==0) recurrent state: batch = wv*16 + g16*4 + r, col nt*4+(c>>2)
    float c_st[NT][4];
    float wm[NT][4];
    #pragma unroll
    for (int nt = 0; nt < NT; ++nt)
        #pragma unroll
        for (int r = 0; r < 4; ++r) { c_st[nt][r] = 0.f; wm[nt][r] = -3.0e38f; }

    const int arow_off = (wv * 16 + cl) * 32 + ((g16 & 1) << 4);  // byte offset inside slice-pair
    const int xrow_b = wv * 16 + cl;

    // prologue: x-part accumulators for t=0
    f32x4 ax[NT];
    {
        int te = d ? (TD - 1) : 0;
        #pragma unroll
        for (int nt = 0; nt < NT; ++nt) { ax[nt][0]=ax[nt][1]=ax[nt][2]=ax[nt][3]=0.f; }
        const __hip_bfloat16* xr = xb + ((size_t)xrow_b * TD + te) * EPD + (g16 << 3);
        #pragma unroll
        for (int kb = 0; kb < NKX; ++kb) {
            bf16x8 a = *reinterpret_cast<const bf16x8*>(xr + kb * 32);
            #pragma unroll
            for (int nt = 0; nt < NT; ++nt) {
                bf16x8 b = *reinterpret_cast<const bf16x8*>(&wlds[nt][NKH + kb][lane][0]);
                ax[nt] = __builtin_amdgcn_mfma_f32_16x16x32_bf16(a, b, ax[nt], 0, 0, 0);
            }
        }
    }

    for (int t = 0; t < TD; ++t) {
        WAITFOR((unsigned)(t + 1) * NWGD);

        const char* hin = h_buf + (size_t)((t & 1) * 2 + d) * (NWGD * SLICE_BYTES);

        // ---- explicit 16-fragment MALL load burst (one pipelined round) ----
        // k = kb*32 + g16*8 + e  ->  slice kb*4+g16, col e: byte = slice*1024 + batch*16 + e*2
        bf16x8 fr[NKH];
        #pragma unroll
        for (int kb = 0; kb < NKH; ++kb) {
            const char* hk = hin + (size_t)(kb * 4 + g16) * SLICE_BYTES;
            fr[kb] = ld_h16(hk + (wv * 16 + cl) * 16);
        }

        f32x4 acc[NT];
        #pragma unroll
        for (int nt = 0; nt < NT; ++nt) acc[nt] = ax[nt];
        #pragma unroll
        for (int kb = 0; kb < NKH; ++kb) {
            #pragma unroll
            for (int nt = 0; nt < NT; ++nt) {
                bf16x8 b = *reinterpret_cast<const bf16x8*>(&wlds[nt][kb][lane][0]);
                acc[nt] = __builtin_amdgcn_mfma_f32_16x16x32_bf16(fr[kb], b, acc[nt], 0, 0, 0);
            }
        }

        // activations: each lane activates its own gate column
        float aown[NT][4];
        #pragma unroll
        for (int nt = 0; nt < NT; ++nt)
            #pragma unroll
            for (int r = 0; r < 4; ++r) {
                float v = acc[nt][r] + bias_n[nt];
                aown[nt][r] = (q == 2) ? tanh_f(v) : sigm_f(v);
            }
        // gather f,g,o to owner lanes (q==0)
        #pragma unroll
        for (int nt = 0; nt < NT; ++nt) {
            #pragma unroll
            for (int r = 0; r < 4; ++r) {
                float fv = __shfl_xor(aown[nt][r], 1, 64);
                float gv = __shfl_xor(aown[nt][r], 2, 64);
                float ov = __shfl_xor(aown[nt][r], 3, 64);
                if (q == 0) {
                    float iv = aown[nt][r];
                    float cn = fmaf(fv, c_st[nt][r], iv * gv);
                    c_st[nt][r] = cn;
                    float hn = ov * tanh_f(cn);
                    wm[nt][r] = fmaxf(wm[nt][r], hn);
                    int batch = wv * 16 + (g16 << 2) + r;
                    hstage[batch][nt * 4 + (c >> 2)] = __float2bfloat16(hn);
                }
            }
        }

        __syncthreads();  // hstage complete (cross-wave)

        // ONE coalesced 8B sc1 store per thread (tid<128): whole 1KB slice block
        if (tid < SLICE_BYTES / 8) {
            unsigned long long v = ((const unsigned long long*)&hstage[0][0])[tid];
            unsigned long long* hout = (unsigned long long*)(
                h_buf + (size_t)(((t + 1) & 1) * 2 + d) * (NWGD * SLICE_BYTES)
                      + (size_t)slice * SLICE_BYTES);
            st64(hout + tid, v);
        }

        ARRIVE();   // per-dir sum -> 64*(t+2)

        // off-critical-path bookkeeping
        if ((t & 31) == 31 && q == 0) {
            int seg = t >> 5;
            if (d) seg = 15 - seg;
            #pragma unroll
            for (int nt = 0; nt < NT; ++nt) {
                int col = j0 + nt * 4 + (c >> 2);
                #pragma unroll
                for (int r = 0; r < 4; ++r) {
                    int batch = wv * 16 + (g16 << 2) + r;
                    wmaxp[((d * 16 + seg) * BD + batch) * HD + col] = wm[nt][r];
                    wm[nt][r] = -3.0e38f;
                }
            }
        }

        // pipelined x-part for t+1 (independent of h_{t+1}; overlaps barrier)
        if (t + 1 < TD) {
            int te = d ? (TD - 2 - t) : (t + 1);
            const __hip_bfloat16* xr = xb + ((size_t)xrow_b * TD + te) * EPD + (g16 << 3);
            f32x4 nx[NT];
            #pragma unroll
            for (int nt = 0; nt < NT; ++nt) { nx[nt][0]=nx[nt][1]=nx[nt][2]=nx[nt][3]=0.f; }
            #pragma unroll
            for (int kb = 0; kb < NKX; ++kb) {
                bf16x8 a = *reinterpret_cast<const bf16x8*>(xr + kb * 32);
                #pragma unroll
                for (int nt = 0; nt < NT; ++nt) {
                    bf16x8 b = *reinterpret_cast<const bf16x8*>(&wlds[nt][NKH + kb][lane][0]);
                    nx[nt] = __builtin_amdgcn_mfma_f32_16x16x32_bf16(a, b, nx[nt], 0, 0, 0);
                }
            }
            #pragma unroll
            for (int nt = 0; nt < NT; ++nt) ax[nt] = nx[nt];
        }
    }
    #undef ARRIVE
    #undef WAITFOR
}

// ---- kernel 2: window-max sum, segment max, decode ----
__global__ __launch_bounds__(256) void pool_decode(const float* __restrict__ wmaxp,
                                                   const float* __restrict__ wdec,
                                                   const float* __restrict__ bdec,
                                                   float* __restrict__ out) {
    __shared__ float red[4 * 256];
    int b = blockIdx.x;
    int tid = threadIdx.x;
    float p[4] = {0.f, 0.f, 0.f, 0.f};
    for (int j = tid; j < HD; j += 256) {
        float m = -3.0e38f;
        #pragma unroll
        for (int s = 0; s < 16; ++s) {
            float v = wmaxp[((0 * 16 + s) * BD + b) * HD + j] +
                      wmaxp[((1 * 16 + s) * BD + b) * HD + j];
            m = fmaxf(m, v);
        }
        m = fmaxf(m, 0.0f);
        #pragma unroll
        for (int q2 = 0; q2 < 4; ++q2) p[q2] = fmaf(m, wdec[q2 * HD + j], p[q2]);
    }
    #pragma unroll
    for (int q2 = 0; q2 < 4; ++q2) red[q2 * 256 + tid] = p[q2];
    __syncthreads();
    for (int off = 128; off > 0; off >>= 1) {
        if (tid < off) {
            #pragma unroll
            for (int q2 = 0; q2 < 4; ++q2) red[q2 * 256 + tid] += red[q2 * 256 + tid + off];
        }
        __syncthreads();
    }
    if (tid < 4) {
        float logit = red[tid * 256] + bdec[tid];
        out[b * 4 + tid] = sigm_f(logit);
    }
}

extern "C" void kernel_launch(void* const* d_in, const int* in_sizes, int n_in,
                              void* d_out, int out_size, void* d_ws, size_t ws_size,
                              hipStream_t stream) {
    (void)in_sizes; (void)n_in; (void)out_size; (void)ws_size;
    const float* x     = (const float*)d_in[0];
    const float* wih_f = (const float*)d_in[1];
    const float* whh_f = (const float*)d_in[2];
    const float* b_f   = (const float*)d_in[3];
    const float* wih_b = (const float*)d_in[4];
    const float* whh_b = (const float*)d_in[5];
    const float* b_b   = (const float*)d_in[6];
    const float* wdec  = (const float*)d_in[7];
    const float* bdec  = (const float*)d_in[8];

    char* ws = (char*)d_ws;
    unsigned* bar = (unsigned*)ws;                           // 2048 B: 16 lines x 128B
    __hip_bfloat16* xb = (__hip_bfloat16*)(ws + 2048);       // BD*TD*EPD*2 = 20,971,520 B
    size_t off = 2048 + (size_t)BD * TD * EPD * 2;
    char* hbuf = ws + off;                                   // 2*2*64*1024 = 262,144 B
    off += (size_t)2 * 2 * NWGD * SLICE_BYTES;
    float* wmaxp = (float*)(ws + off);                       // 2*16*BD*HD*4 = 4,194,304 B

    hipMemsetAsync(bar, 0, 2048, stream);
    cast_x_kernel<<<dim3((BD * TD * EPD) / 256), dim3(256), 0, stream>>>(x, xb);

    const __hip_bfloat16* xb_c = xb;
    char* hbuf_p = hbuf;
    float* wmax_p = wmaxp;
    unsigned* bar_p = bar;
    void* args[] = {(void*)&xb_c, (void*)&wih_f, (void*)&whh_f, (void*)&b_f,
                    (void*)&wih_b, (void*)&whh_b, (void*)&b_b,
                    (void*)&hbuf_p, (void*)&wmax_p, (void*)&bar_p};
    hipLaunchCooperativeKernel((void*)lstm_persistent, dim3(NWG), dim3(256), args, 0, stream);

    pool_decode<<<dim3(BD), dim3(256), 0, stream>>>(wmaxp, wdec, bdec, (float*)d_out);
}